// Round 7
// baseline (206.069 us; speedup 1.0000x reference)
//
#include <hip/hip_runtime.h>
#include <stdint.h>
#include <stddef.h>

typedef __bf16 bf16;
typedef bf16 bf16x4 __attribute__((ext_vector_type(4)));
typedef bf16 bf16x8 __attribute__((ext_vector_type(8)));
typedef float f32x4 __attribute__((ext_vector_type(4)));

#define DEVI static __device__ __forceinline__

// B=2, N=4096, DIM=512, HEADS=8, DHEAD=64, INNER=512

DEVI f32x4 mfma16(bf16x8 a, bf16x8 b, f32x4 c) {
  return __builtin_amdgcn_mfma_f32_16x16x32_bf16(a, b, c, 0, 0, 0);
}

DEVI void gload_lds16(const bf16* g, bf16* lds) {
  __builtin_amdgcn_global_load_lds(
      (const __attribute__((address_space(1))) unsigned int*)g,
      (__attribute__((address_space(3))) unsigned int*)lds, 16, 0, 0);
}

// kv bit-permutation for in-register P:
// sigma(32kc+16u+4hi+r) = 32kc+8hi+4u+r.  S^T computed against K rows staged
// in sigma order makes the S^T D-fragment coincide with the PV A-fragment.
DEVI int sigma64(int r) { return (r & 0x23) | ((r & 0xC) << 1) | ((r & 0x10) >> 2); }

// LDS tiles are [R][64] bf16 (128 B rows). XOR-swizzle involution on 16B
// granules (slots of 8 elems): slot' = slot ^ (row&7).
// global_load_lds writes linearly (LDS slot = lane&7, row = base+lane>>3), so
// the SOURCE column slot is pre-swizzled: src_slot = (lane&7) ^ (row&7).
// Every read of logical slot cs fetches LDS slot cs ^ (row&7). All fragment
// rows have row&7 == lane&7, so reads are conflict-free (rule #21 / T2).
// Fragment k-slot for 16x16x32: cs = kc*4 + (lane>>4).

// ---------- prep: x f32->bf16, w_qkv^T, w_out^T (one launch) ----------
DEVI void tcvt_tile(const float* __restrict__ in, bf16* __restrict__ out,
                    int Kd, int Nd, int bx, int by, bf16* T) {
  const int k0 = by * 64, n0 = bx * 64;
  const int r = threadIdx.x >> 2;
  const int c0 = (threadIdx.x & 3) * 16;
  const float* src = in + (size_t)(k0 + r) * Nd + n0 + c0;
#pragma unroll
  for (int j = 0; j < 16; ++j) T[(c0 + j) * 80 + r] = (bf16)src[j];
  __syncthreads();
  bf16* dst = out + (size_t)(n0 + r) * Kd + k0 + c0;
  const bf16* s = T + r * 80 + c0;
#pragma unroll
  for (int j = 0; j < 2; ++j)
    *reinterpret_cast<bf16x8*>(dst + j * 8) =
        *reinterpret_cast<const bf16x8*>(s + j * 8);
}

__global__ __launch_bounds__(256) void prep_kernel(
    const float* __restrict__ x, bf16* __restrict__ xb,
    const float* __restrict__ wq, bf16* __restrict__ wqT,
    const float* __restrict__ wo, bf16* __restrict__ woT) {
  __shared__ bf16 T[64 * 80];
  const int blk = blockIdx.x;
  if (blk < 2048) {
    int i = blk * 256 + threadIdx.x;
    const int n4 = 8192 * 512 / 4, stride = 2048 * 256;
    for (; i < n4; i += stride) {
      f32x4 v = reinterpret_cast<const f32x4*>(x)[i];
      bf16x4 o;
      o[0] = (bf16)v[0]; o[1] = (bf16)v[1]; o[2] = (bf16)v[2]; o[3] = (bf16)v[3];
      reinterpret_cast<bf16x4*>(xb)[i] = o;
    }
  } else if (blk < 2240) {
    const int t = blk - 2048;
    tcvt_tile(wq, wqT, 512, 1536, t % 24, t / 24, T);
  } else {
    const int t = blk - 2240;
    tcvt_tile(wo, woT, 512, 512, t % 8, t / 8, T);
  }
}

// ---------- GEMM<0>: qkv = x_bf @ wqkvT -> Q,K row-major per head, V^T ----
// 128x128 tile, BK=64, 2-phase dbuf prefetch, 4 waves (2x2).
__global__ __launch_bounds__(256) void gemm_kernel(
    const bf16* __restrict__ A, const bf16* __restrict__ BT,
    bf16* __restrict__ qo, bf16* __restrict__ ko, bf16* __restrict__ vto) {
  constexpr int K = 512;
  __shared__ __align__(16) bf16 SM[4 * 128 * 64];   // 64 KB: dbuf A/B + epilogue
  const int lane = threadIdx.x & 63;
  const int w = threadIdx.x >> 6;
  const int hi = lane >> 4;
  const int wm = w >> 1, wn = w & 1;
  const int m0 = blockIdx.y * 128, n0 = blockIdx.x * 128;
  const int sl = lane >> 3;
  const int ssc = ((lane & 7) ^ sl) * 8;

  auto AsB = [&](int bi) { return SM + bi * 8192; };
  auto BsB = [&](int bi) { return SM + 16384 + bi * 8192; };

  auto stage = [&](int bi, int kt) {
    const int k0 = kt * 64;
#pragma unroll
    for (int c = 0; c < 4; ++c) {
      const int ca = w * 4 + c;
      const int trow = ca * 8 + sl;
      gload_lds16(A + (size_t)(m0 + trow) * K + k0 + ssc, AsB(bi) + ca * 512);
      gload_lds16(BT + (size_t)(n0 + trow) * K + k0 + ssc, BsB(bi) + ca * 512);
    }
  };

  f32x4 acc[4][4];
#pragma unroll
  for (int i = 0; i < 4; ++i)
#pragma unroll
    for (int j = 0; j < 4; ++j) acc[i][j] = {0.f, 0.f, 0.f, 0.f};

  stage(0, 0);
  asm volatile("s_waitcnt vmcnt(0)" ::: "memory");
  __builtin_amdgcn_s_barrier();

  for (int kt = 0; kt < K / 64; ++kt) {
    const int cur = kt & 1;
    if (kt < K / 64 - 1) stage(cur ^ 1, kt + 1);
    const bf16* As = AsB(cur);
    const bf16* Bs = BsB(cur);
#pragma unroll
    for (int kc = 0; kc < 2; ++kc) {
      const int csw = ((kc * 4 + hi) ^ (lane & 7)) * 8;
      bf16x8 af[4], bfr[4];
#pragma unroll
      for (int mi = 0; mi < 4; ++mi)
        af[mi] = *reinterpret_cast<const bf16x8*>(
            &As[(wm * 64 + mi * 16 + (lane & 15)) * 64 + csw]);
#pragma unroll
      for (int ni = 0; ni < 4; ++ni)
        bfr[ni] = *reinterpret_cast<const bf16x8*>(
            &Bs[(wn * 64 + ni * 16 + (lane & 15)) * 64 + csw]);
      __builtin_amdgcn_s_setprio(1);
#pragma unroll
      for (int mi = 0; mi < 4; ++mi)
#pragma unroll
        for (int ni = 0; ni < 4; ++ni)
          acc[mi][ni] = mfma16(af[mi], bfr[ni], acc[mi][ni]);
      __builtin_amdgcn_s_setprio(0);
    }
    asm volatile("s_waitcnt vmcnt(0)" ::: "memory");
    __builtin_amdgcn_s_barrier();
  }

  // ---- epilogue via LDS (SM free after final barrier) ----
  if (n0 < 1024) {
    // Q/K blocks: row-major SM[m][col], then 16B-vector row stores
#pragma unroll
    for (int mi = 0; mi < 4; ++mi)
#pragma unroll
      for (int ni = 0; ni < 4; ++ni)
#pragma unroll
        for (int r = 0; r < 4; ++r) {
          const int rl = wm * 64 + mi * 16 + hi * 4 + r;
          const int cl = wn * 64 + ni * 16 + (lane & 15);
          SM[rl * 136 + cl] = (bf16)acc[mi][ni][r];
        }
    __syncthreads();
    const int rl = threadIdx.x >> 1, hh = threadIdx.x & 1;
    const int m = m0 + rl, b = m >> 12, n = m & 4095;
    const int colg = n0 + hh * 64;
    const int sec = colg >> 9, h = (colg & 511) >> 6;
    bf16* dst = (sec ? ko : qo) + ((size_t)(b * 8 + h) * 4096 + n) * 64;
    const bf16* srcp = SM + rl * 136 + hh * 64;
#pragma unroll
    for (int j = 0; j < 8; ++j)
      *reinterpret_cast<bf16x8*>(dst + j * 8) =
          *reinterpret_cast<const bf16x8*>(srcp + j * 8);
  } else {
    // V blocks: transpose via SM, coalesced write to vto [bh][d][n]
#pragma unroll
    for (int mi = 0; mi < 4; ++mi)
#pragma unroll
      for (int ni = 0; ni < 4; ++ni)
#pragma unroll
        for (int r = 0; r < 4; ++r) {
          const int rl = wm * 64 + mi * 16 + hi * 4 + r;      // local row (n)
          const int cl = wn * 64 + ni * 16 + (lane & 15);     // local col (d)
          SM[cl * 136 + rl] = (bf16)acc[mi][ni][r];
        }
    __syncthreads();
    const int b = m0 >> 12, nb = m0 & 4095;
    const int cl = threadIdx.x >> 1, half = threadIdx.x & 1;
    const int jj = (n0 - 1024) + cl, h = jj >> 6, d = jj & 63;
    bf16* dst = vto + ((size_t)(b * 8 + h) * 64 + d) * 4096 + nb + half * 64;
    const bf16* srcp = SM + cl * 136 + half * 64;
#pragma unroll
    for (int j = 0; j < 8; ++j)
      *reinterpret_cast<bf16x8*>(dst + j * 8) =
          *reinterpret_cast<const bf16x8*>(srcp + j * 8);
  }
}

// ---------- fused relu-attention (round 7: 3-buf counted-vmcnt pipeline) ----
// grid (32 q-tiles, 16 bh). 4 waves/block; wave owns 32 q rows; 64 kv iters.
// Ring of 3 KV buffers: per iter STAGE(t+1) -> vmcnt(4) -> s_barrier ->
// compute(t). No drain-0 in the loop (T4); stage latency hides under a full
// iteration. K rows staged in sigma64 order -> S^T D-frag IS the PV A-frag
// after relu+pack (in-register P). scale deferred to final O write.
__global__ __launch_bounds__(256, 2) void attn_kernel(
    const bf16* __restrict__ Q, const bf16* __restrict__ Kg,
    const bf16* __restrict__ VT, float* __restrict__ out) {
  __shared__ __align__(16) bf16 KV[6 * 4096];  // Ks: [0,12288), Vs: [12288,24576)
  const int lane = threadIdx.x & 63;
  const int w = threadIdx.x >> 6;
  const int hi = lane >> 4;
  const int ql = lane & 15;
  const int bh = blockIdx.y;
  const int q0 = blockIdx.x * 128 + w * 32;
  const bf16* Qh = Q + (size_t)bh * 4096 * 64;
  const bf16* Kh = Kg + (size_t)bh * 4096 * 64;
  const bf16* Vh = VT + (size_t)bh * 64 * 4096;

  const int sl = lane >> 3;
  const int ssc = ((lane & 7) ^ sl) * 8;           // pre-swizzled source col

  // global src pointers (advance by `step` per staged tile) + LDS dest offsets
  const bf16* gs[4];
  int dstoff[4], step;
  if (w < 2) {
#pragma unroll
    for (int c = 0; c < 4; ++c) {
      const int rho = (w * 4 + c) * 8 + sl;        // physical LDS row
      gs[c] = Kh + sigma64(rho) * 64 + ssc;        // K: sigma-permuted rows
      dstoff[c] = (w * 4 + c) * 512;
    }
    step = 64 * 64;                                // next kv chunk: +64 rows
  } else {
#pragma unroll
    for (int c = 0; c < 4; ++c) {
      const int d = ((w - 2) * 4 + c) * 8 + sl;    // VT row (d)
      gs[c] = Vh + (size_t)d * 4096 + ssc;
      dstoff[c] = 12288 + ((w - 2) * 4 + c) * 512;
    }
    step = 64;                                     // next kv chunk: +64 cols
  }

  auto stageN = [&](int bi) {
#pragma unroll
    for (int c = 0; c < 4; ++c) {
      gload_lds16(gs[c], KV + bi * 4096 + dstoff[c]);
      gs[c] += step;
    }
  };

  // hoisted LDS read lane-offsets (elements): row=ql part + swizzled k-slot
  int lro[2];
#pragma unroll
  for (int kc = 0; kc < 2; ++kc)
    lro[kc] = ql * 64 + (((kc * 4 + hi) ^ (lane & 7)) * 8);

  bf16x8 qf[2][2];
#pragma unroll
  for (int qb = 0; qb < 2; ++qb)
#pragma unroll
    for (int kc = 0; kc < 2; ++kc)
      qf[qb][kc] = *reinterpret_cast<const bf16x8*>(
          &Qh[(size_t)(q0 + qb * 16 + ql) * 64 + kc * 32 + hi * 8]);

  f32x4 o[2][4];
#pragma unroll
  for (int qb = 0; qb < 2; ++qb)
#pragma unroll
    for (int db = 0; db < 4; ++db) o[qb][db] = {0.f, 0.f, 0.f, 0.f};

  stageN(0);                                       // prologue: tile 0 in flight
  int buf = 0, bufn = 1;

  for (int it = 0; it < 64; ++it) {
    if (it < 63) {
      stageN(bufn);                                // issue t+1 (8 outstanding)
      asm volatile("s_waitcnt vmcnt(4)" ::: "memory");  // t's 4 loads landed
    } else {
      asm volatile("s_waitcnt vmcnt(0)" ::: "memory");
    }
    __builtin_amdgcn_s_barrier();                  // all waves' tile-t ready

    const bf16* Kb = KV + buf * 4096;

    // S^T = K_staged Q^T : s[qb][kvb], lane: col=q=ql, rows=phys kv
    f32x4 s[2][4];
#pragma unroll
    for (int qb = 0; qb < 2; ++qb)
#pragma unroll
      for (int kvb = 0; kvb < 4; ++kvb) s[qb][kvb] = {0.f, 0.f, 0.f, 0.f};
#pragma unroll
    for (int kc = 0; kc < 2; ++kc) {
      const bf16* kbp = Kb + lro[kc];
      bf16x8 kf[4];
#pragma unroll
      for (int kvb = 0; kvb < 4; ++kvb)
        kf[kvb] = *reinterpret_cast<const bf16x8*>(kbp + kvb * 1024);
      __builtin_amdgcn_s_setprio(1);
#pragma unroll
      for (int qb = 0; qb < 2; ++qb)
#pragma unroll
        for (int kvb = 0; kvb < 4; ++kvb)
          s[qb][kvb] = mfma16(kf[kvb], qf[qb][kc], s[qb][kvb]);
      __builtin_amdgcn_s_setprio(0);
    }

    // PV: pack P in-register (sigma makes S^T frag == PV A-frag) and MFMA
#pragma unroll
    for (int kc = 0; kc < 2; ++kc) {
      const bf16* vbp = Kb + 12288 + lro[kc];
      bf16x8 vf[4];
#pragma unroll
      for (int db = 0; db < 4; ++db)
        vf[db] = *reinterpret_cast<const bf16x8*>(vbp + db * 1024);
      bf16x8 pa[2];
#pragma unroll
      for (int qb = 0; qb < 2; ++qb)
#pragma unroll
        for (int u = 0; u < 2; ++u)
#pragma unroll
          for (int r = 0; r < 4; ++r)
            pa[qb][u * 4 + r] = (bf16)fmaxf(s[qb][2 * kc + u][r], 0.f);
      __builtin_amdgcn_s_setprio(1);
#pragma unroll
      for (int qb = 0; qb < 2; ++qb)
#pragma unroll
        for (int db = 0; db < 4; ++db)
          o[qb][db] = mfma16(pa[qb], vf[db], o[qb][db]);
      __builtin_amdgcn_s_setprio(0);
    }

    buf = bufn;
    bufn = (bufn == 2) ? 0 : bufn + 1;
  }

  const int b = bh >> 3, h = bh & 7;
#pragma unroll
  for (int qb = 0; qb < 2; ++qb)
#pragma unroll
    for (int db = 0; db < 4; ++db)
#pragma unroll
      for (int r = 0; r < 4; ++r) {
        const int n = q0 + qb * 16 + hi * 4 + r;
        const int dcol = db * 16 + ql;
        out[((size_t)(b * 4096 + n)) * 512 + h * 64 + dcol] = o[qb][db][r] * 0.125f;
      }
}

// ---------- fused LayerNorm + output GEMM + bias ----------
// grid (4, 64) = 256 blocks, 128x128 tile. Phase A: per-row mean/rstd via
// shuffle (2 threads/row). K-loop: A-operand reg-staged from f32 attn_out
// with normalize+cvt+swizzled ds_write; B via gload_lds; MFMA; bias epilogue.
__global__ __launch_bounds__(256) void lngemm_kernel(
    const float* __restrict__ X,      // attn_out [8192][512] f32
    const bf16* __restrict__ BT,      // woutT [512][512] bf16
    const float* __restrict__ gamma, const float* __restrict__ beta,
    const float* __restrict__ bias, float* __restrict__ out) {
  __shared__ __align__(16) bf16 As[128 * 64];
  __shared__ __align__(16) bf16 Bs[128 * 64];
  __shared__ float gG[512];
  __shared__ float gB[512];
  __shared__ float MR[128 * 2];
  const int tid = threadIdx.x;
  const int lane = tid & 63;
  const int w = tid >> 6;
  const int hi = lane >> 4;
  const int wm = w >> 1, wn = w & 1;
  const int m0 = blockIdx.y * 128, n0 = blockIdx.x * 128;
  const int sl = lane >> 3;
  const int ssc = ((lane & 7) ^ sl) * 8;

  // preload gamma/beta
  {
    const int i = tid * 2;
    gG[i] = gamma[i]; gG[i + 1] = gamma[i + 1];
    gB[i] = beta[i];  gB[i + 1] = beta[i + 1];
  }

  // Phase A: stats (row = tid>>1, each thread one half-row of 256 f32)
  {
    const int row = tid >> 1, hf = tid & 1;
    const float* src = X + (size_t)(m0 + row) * 512 + hf * 256;
    float s = 0.f, ss = 0.f;
#pragma unroll
    for (int j = 0; j < 64; ++j) {
      f32x4 v = reinterpret_cast<const f32x4*>(src)[j];
#pragma unroll
      for (int q = 0; q < 4; ++q) { s += v[q]; ss += v[q] * v[q]; }
    }
    s += __shfl_xor(s, 1);
    ss += __shfl_xor(ss, 1);
    if (hf == 0) {
      const float mean = s * (1.f / 512.f);
      const float var = ss * (1.f / 512.f) - mean * mean;
      MR[row * 2] = mean;
      MR[row * 2 + 1] = rsqrtf(var + 1e-5f);
    }
  }

  f32x4 acc[4][4];
#pragma unroll
  for (int i = 0; i < 4; ++i)
#pragma unroll
    for (int j = 0; j < 4; ++j) acc[i][j] = {0.f, 0.f, 0.f, 0.f};

  for (int kt = 0; kt < 8; ++kt) {
    __syncthreads();   // prev compute done (and stats/gG visible at kt=0)
    // B stage first (VMEM latency hides under A's VALU staging)
#pragma unroll
    for (int c = 0; c < 4; ++c) {
      const int ca = w * 4 + c;
      const int trow = ca * 8 + sl;
      gload_lds16(BT + (size_t)(n0 + trow) * 512 + kt * 64 + ssc, Bs + ca * 512);
    }
    // A stage: row = tid>>1, k-slots si = 4*(tid&1)+q; normalize -> bf16 ->
    // swizzled ds_write (slot' = si ^ (row&7))
    {
      const int row = tid >> 1, hf = tid & 1;
      const float mean = MR[row * 2], rstd = MR[row * 2 + 1];
      const float* src = X + (size_t)(m0 + row) * 512 + kt * 64 + hf * 32;
      const float* gg = gG + kt * 64 + hf * 32;
      const float* bb = gB + kt * 64 + hf * 32;
#pragma unroll
      for (int q = 0; q < 4; ++q) {
        const int si = hf * 4 + q;
        f32x4 v0 = reinterpret_cast<const f32x4*>(src)[q * 2];
        f32x4 v1 = reinterpret_cast<const f32x4*>(src)[q * 2 + 1];
        bf16x8 ov;
#pragma unroll
        for (int j = 0; j < 4; ++j) {
          ov[j] = (bf16)((v0[j] - mean) * rstd * gg[q * 8 + j] + bb[q * 8 + j]);
          ov[4 + j] = (bf16)((v1[j] - mean) * rstd * gg[q * 8 + 4 + j] + bb[q * 8 + 4 + j]);
        }
        *reinterpret_cast<bf16x8*>(&As[row * 64 + ((si ^ (row & 7)) * 8)]) = ov;
      }
    }
    __syncthreads();   // drains vm (B) + lgkm (A writes)
#pragma unroll
    for (int kc = 0; kc < 2; ++kc) {
      const int csw = ((kc * 4 + hi) ^ (lane & 7)) * 8;
      bf16x8 af[4], bfr[4];
#pragma unroll
      for (int mi = 0; mi < 4; ++mi)
        af[mi] = *reinterpret_cast<const bf16x8*>(
            &As[(wm * 64 + mi * 16 + (lane & 15)) * 64 + csw]);
#pragma unroll
      for (int ni = 0; ni < 4; ++ni)
        bfr[ni] = *reinterpret_cast<const bf16x8*>(
            &Bs[(wn * 64 + ni * 16 + (lane & 15)) * 64 + csw]);
      __builtin_amdgcn_s_setprio(1);
#pragma unroll
      for (int mi = 0; mi < 4; ++mi)
#pragma unroll
        for (int ni = 0; ni < 4; ++ni)
          acc[mi][ni] = mfma16(af[mi], bfr[ni], acc[mi][ni]);
      __builtin_amdgcn_s_setprio(0);
    }
  }

#pragma unroll
  for (int mi = 0; mi < 4; ++mi)
#pragma unroll
    for (int ni = 0; ni < 4; ++ni)
#pragma unroll
      for (int r = 0; r < 4; ++r) {
        const int m = m0 + wm * 64 + mi * 16 + hi * 4 + r;
        const int col = n0 + wn * 64 + ni * 16 + (lane & 15);
        out[(size_t)m * 512 + col] = acc[mi][ni][r] + bias[col];
      }
}

extern "C" void kernel_launch(void* const* d_in, const int* in_sizes, int n_in,
                              void* d_out, int out_size, void* d_ws, size_t ws_size,
                              hipStream_t stream) {
  const float* x = (const float*)d_in[0];       // [2,4096,512]
  const float* w_qkv = (const float*)d_in[1];   // [512,1536]
  const float* ln_g = (const float*)d_in[2];    // [512]
  const float* ln_b = (const float*)d_in[3];    // [512]
  const float* w_out = (const float*)d_in[4];   // [512,512]
  const float* b_out = (const float*)d_in[5];   // [512]
  float* out = (float*)d_out;                   // [2,4096,512] f32

  char* ws = (char*)d_ws;
  size_t off = 0;
  auto alloc = [&](size_t bytes) {
    void* p = ws + off;
    off += (bytes + 255) & ~(size_t)255;
    return p;
  };
  bf16* x_bf = (bf16*)alloc((size_t)8192 * 512 * 2);
  bf16* wqkvT = (bf16*)alloc((size_t)1536 * 512 * 2);
  bf16* woutT = (bf16*)alloc((size_t)512 * 512 * 2);
  bf16* qbuf = (bf16*)alloc((size_t)16 * 4096 * 64 * 2);
  bf16* kbuf = (bf16*)alloc((size_t)16 * 4096 * 64 * 2);
  bf16* vtbuf = (bf16*)alloc((size_t)16 * 64 * 4096 * 2);
  float* attn_out = (float*)alloc((size_t)8192 * 512 * 4);

  // 1) prep: cvt + both weight transposes (one launch)
  prep_kernel<<<2304, 256, 0, stream>>>(x, x_bf, w_qkv, wqkvT, w_out, woutT);

  // 2) qkv = x @ w_qkv -> Q,K (row-major per head), V transposed [d][n]
  gemm_kernel<<<dim3(12, 64), 256, 0, stream>>>(x_bf, wqkvT, qbuf, kbuf, vtbuf);

  // 3) fused relu-attention -> attn_out f32 [8192][512]
  attn_kernel<<<dim3(32, 16), 256, 0, stream>>>(qbuf, kbuf, vtbuf, attn_out);

  // 4) fused layernorm + out-projection + bias -> f32
  lngemm_kernel<<<dim3(4, 64), 256, 0, stream>>>(attn_out, woutT, ln_g, ln_b,
                                                 b_out, out);
}

// Round 8
// 180.375 us; speedup vs baseline: 1.1424x; 1.1424x over previous
//
#include <hip/hip_runtime.h>
#include <stdint.h>
#include <stddef.h>

typedef __bf16 bf16;
typedef bf16 bf16x4 __attribute__((ext_vector_type(4)));
typedef bf16 bf16x8 __attribute__((ext_vector_type(8)));
typedef float f32x4 __attribute__((ext_vector_type(4)));

#define DEVI static __device__ __forceinline__

// B=2, N=4096, DIM=512, HEADS=8, DHEAD=64, INNER=512

DEVI f32x4 mfma16(bf16x8 a, bf16x8 b, f32x4 c) {
  return __builtin_amdgcn_mfma_f32_16x16x32_bf16(a, b, c, 0, 0, 0);
}

DEVI void gload_lds16(const bf16* g, bf16* lds) {
  __builtin_amdgcn_global_load_lds(
      (const __attribute__((address_space(1))) unsigned int*)g,
      (__attribute__((address_space(3))) unsigned int*)lds, 16, 0, 0);
}

// kv bit-permutation for in-register P:
// sigma(32kc+16u+4hi+r) = 32kc+8hi+4u+r.  S^T computed against K rows staged
// in sigma order makes the S^T D-fragment coincide with the PV A-fragment.
DEVI int sigma64(int r) { return (r & 0x23) | ((r & 0xC) << 1) | ((r & 0x10) >> 2); }

// LDS tiles are [R][64] bf16 (128 B rows). XOR-swizzle involution on 16B
// granules (slots of 8 elems): slot' = slot ^ (row&7).
// global_load_lds writes linearly (LDS slot = lane&7, row = base+lane>>3), so
// the SOURCE column slot is pre-swizzled: src_slot = (lane&7) ^ (row&7).
// Every read of logical slot cs fetches LDS slot cs ^ (row&7). Conflict-free
// (rule #21 / T2). Fragment k-slot for 16x16x32: cs = kc*4 + (lane>>4).
//
// Pipeline pattern (T3/T4 minimum, 2-deep): prologue stages tiles 0,1; each
// iter: wait vmcnt(=1 stage) -> barrier -> compute(t) -> barrier ->
// stage(t+2). Per-wave vmcnt before the barrier makes all waves' tile-t
// loads visible after it; no drain-0 in the loop.

// ---------- prep: x f32->bf16, w_qkv^T, w_out^T (one launch) ----------
DEVI void tcvt_tile(const float* __restrict__ in, bf16* __restrict__ out,
                    int Kd, int Nd, int bx, int by, bf16* T) {
  const int k0 = by * 64, n0 = bx * 64;
  const int r = threadIdx.x >> 2;
  const int c0 = (threadIdx.x & 3) * 16;
  const float* src = in + (size_t)(k0 + r) * Nd + n0 + c0;
#pragma unroll
  for (int j = 0; j < 16; ++j) T[(c0 + j) * 80 + r] = (bf16)src[j];
  __syncthreads();
  bf16* dst = out + (size_t)(n0 + r) * Kd + k0 + c0;
  const bf16* s = T + r * 80 + c0;
#pragma unroll
  for (int j = 0; j < 2; ++j)
    *reinterpret_cast<bf16x8*>(dst + j * 8) =
        *reinterpret_cast<const bf16x8*>(s + j * 8);
}

__global__ __launch_bounds__(256) void prep_kernel(
    const float* __restrict__ x, bf16* __restrict__ xb,
    const float* __restrict__ wq, bf16* __restrict__ wqT,
    const float* __restrict__ wo, bf16* __restrict__ woT) {
  __shared__ bf16 T[64 * 80];
  const int blk = blockIdx.x;
  if (blk < 2048) {
    int i = blk * 256 + threadIdx.x;
    const int n4 = 8192 * 512 / 4, stride = 2048 * 256;
    for (; i < n4; i += stride) {
      f32x4 v = reinterpret_cast<const f32x4*>(x)[i];
      bf16x4 o;
      o[0] = (bf16)v[0]; o[1] = (bf16)v[1]; o[2] = (bf16)v[2]; o[3] = (bf16)v[3];
      reinterpret_cast<bf16x4*>(xb)[i] = o;
    }
  } else if (blk < 2240) {
    const int t = blk - 2048;
    tcvt_tile(wq, wqT, 512, 1536, t % 24, t / 24, T);
  } else {
    const int t = blk - 2240;
    tcvt_tile(wo, woT, 512, 512, t % 8, t / 8, T);
  }
}

// ---------- GEMM: A[M][512] bf16 row-major, BT[N][512] bf16 row-major ------
// 128x128 tile, BK=64, 2-deep counted dbuf pipeline, 4 waves (2x2).
// EPI 0: Q,K row-major per head + V^T via LDS epilogue (16B stores).
// EPI 1: out f32 [M][512] = acc + bias[col].
template <int EPI>
__global__ __launch_bounds__(256) void gemm_kernel(
    const bf16* __restrict__ A, const bf16* __restrict__ BT,
    bf16* __restrict__ qo, bf16* __restrict__ ko, bf16* __restrict__ vto,
    const float* __restrict__ bias, float* __restrict__ fo) {
  constexpr int K = 512;
  __shared__ __align__(16) bf16 SM[4 * 128 * 64];   // 64 KB: dbuf A/B + epilogue
  const int lane = threadIdx.x & 63;
  const int w = threadIdx.x >> 6;
  const int hi = lane >> 4;
  const int wm = w >> 1, wn = w & 1;
  const int m0 = blockIdx.y * 128, n0 = blockIdx.x * 128;
  const int sl = lane >> 3;
  const int ssc = ((lane & 7) ^ sl) * 8;

  auto AsB = [&](int bi) { return SM + bi * 8192; };
  auto BsB = [&](int bi) { return SM + 16384 + bi * 8192; };

  auto stage = [&](int bi, int kt) {
    const int k0 = kt * 64;
#pragma unroll
    for (int c = 0; c < 4; ++c) {
      const int ca = w * 4 + c;
      const int trow = ca * 8 + sl;
      gload_lds16(A + (size_t)(m0 + trow) * K + k0 + ssc, AsB(bi) + ca * 512);
      gload_lds16(BT + (size_t)(n0 + trow) * K + k0 + ssc, BsB(bi) + ca * 512);
    }
  };

  f32x4 acc[4][4];
#pragma unroll
  for (int i = 0; i < 4; ++i)
#pragma unroll
    for (int j = 0; j < 4; ++j) acc[i][j] = {0.f, 0.f, 0.f, 0.f};

  stage(0, 0);
  stage(1, 1);

  for (int kt = 0; kt < 8; ++kt) {
    const int cur = kt & 1;
    if (kt < 7) {
      asm volatile("s_waitcnt vmcnt(8)" ::: "memory");   // tile kt landed
    } else {
      asm volatile("s_waitcnt vmcnt(0)" ::: "memory");
    }
    __builtin_amdgcn_s_barrier();       // all waves' tile-kt loads visible
    const bf16* As = AsB(cur);
    const bf16* Bs = BsB(cur);
#pragma unroll
    for (int kc = 0; kc < 2; ++kc) {
      const int csw = ((kc * 4 + hi) ^ (lane & 7)) * 8;
      bf16x8 af[4], bfr[4];
#pragma unroll
      for (int mi = 0; mi < 4; ++mi)
        af[mi] = *reinterpret_cast<const bf16x8*>(
            &As[(wm * 64 + mi * 16 + (lane & 15)) * 64 + csw]);
#pragma unroll
      for (int ni = 0; ni < 4; ++ni)
        bfr[ni] = *reinterpret_cast<const bf16x8*>(
            &Bs[(wn * 64 + ni * 16 + (lane & 15)) * 64 + csw]);
      __builtin_amdgcn_s_setprio(1);
#pragma unroll
      for (int mi = 0; mi < 4; ++mi)
#pragma unroll
        for (int ni = 0; ni < 4; ++ni)
          acc[mi][ni] = mfma16(af[mi], bfr[ni], acc[mi][ni]);
      __builtin_amdgcn_s_setprio(0);
    }
    __builtin_amdgcn_s_barrier();       // all waves done reading buf cur
    if (kt + 2 < 8) stage(cur, kt + 2); // overwrite cur with tile kt+2
  }

  if (EPI == 0) {
    // ---- epilogue via LDS (SM free after final barrier) ----
    if (n0 < 1024) {
      // Q/K blocks: row-major SM[m][col], then 16B-vector row stores
#pragma unroll
      for (int mi = 0; mi < 4; ++mi)
#pragma unroll
        for (int ni = 0; ni < 4; ++ni)
#pragma unroll
          for (int r = 0; r < 4; ++r) {
            const int rl = wm * 64 + mi * 16 + hi * 4 + r;
            const int cl = wn * 64 + ni * 16 + (lane & 15);
            SM[rl * 136 + cl] = (bf16)acc[mi][ni][r];
          }
      __syncthreads();
      const int rl = threadIdx.x >> 1, hh = threadIdx.x & 1;
      const int m = m0 + rl, b = m >> 12, n = m & 4095;
      const int colg = n0 + hh * 64;
      const int sec = colg >> 9, h = (colg & 511) >> 6;
      bf16* dst = (sec ? ko : qo) + ((size_t)(b * 8 + h) * 4096 + n) * 64;
      const bf16* srcp = SM + rl * 136 + hh * 64;
#pragma unroll
      for (int j = 0; j < 8; ++j)
        *reinterpret_cast<bf16x8*>(dst + j * 8) =
            *reinterpret_cast<const bf16x8*>(srcp + j * 8);
    } else {
      // V blocks: transpose via SM, coalesced write to vto [bh][d][n]
#pragma unroll
      for (int mi = 0; mi < 4; ++mi)
#pragma unroll
        for (int ni = 0; ni < 4; ++ni)
#pragma unroll
          for (int r = 0; r < 4; ++r) {
            const int rl = wm * 64 + mi * 16 + hi * 4 + r;      // local row (n)
            const int cl = wn * 64 + ni * 16 + (lane & 15);     // local col (d)
            SM[cl * 136 + rl] = (bf16)acc[mi][ni][r];
          }
      __syncthreads();
      const int b = m0 >> 12, nb = m0 & 4095;
      const int cl = threadIdx.x >> 1, half = threadIdx.x & 1;
      const int jj = (n0 - 1024) + cl, h = jj >> 6, d = jj & 63;
      bf16* dst = vto + ((size_t)(b * 8 + h) * 64 + d) * 4096 + nb + half * 64;
      const bf16* srcp = SM + cl * 136 + half * 64;
#pragma unroll
      for (int j = 0; j < 8; ++j)
        *reinterpret_cast<bf16x8*>(dst + j * 8) =
            *reinterpret_cast<const bf16x8*>(srcp + j * 8);
    }
    return;
  }

#pragma unroll
  for (int mi = 0; mi < 4; ++mi)
#pragma unroll
    for (int ni = 0; ni < 4; ++ni)
#pragma unroll
      for (int r = 0; r < 4; ++r) {
        const int m = m0 + wm * 64 + mi * 16 + hi * 4 + r;
        const int col = n0 + wn * 64 + ni * 16 + (lane & 15);
        fo[(size_t)m * 512 + col] = acc[mi][ni][r] + bias[col];
      }
}

// ---------- fused relu-attention (round 8: z=2 + 2-deep counted dbuf) ------
// grid (32 q-tiles, 16 bh, 2 kv-halves). 4 waves/block; wave owns 32 q rows;
// 32 kv iters per block. Dbuf (32 KB) with 2-deep prefetch: wait vmcnt(4) ->
// barrier -> compute(t) -> barrier -> stage(t+2). K rows staged in sigma64
// order -> S^T D-frag IS the PV A-frag after relu+pack (in-register P).
// scale deferred to final O write (relu(s*c) = c*relu(s), c>0).
__global__ __launch_bounds__(256, 4) void attn_kernel(
    const bf16* __restrict__ Q, const bf16* __restrict__ Kg,
    const bf16* __restrict__ VT, float* __restrict__ out0,
    float* __restrict__ out1) {
  __shared__ __align__(16) bf16 KV[4 * 4096];  // K: bi*4096; V: 8192+bi*4096
  const int lane = threadIdx.x & 63;
  const int w = threadIdx.x >> 6;
  const int hi = lane >> 4;
  const int ql = lane & 15;
  const int bh = blockIdx.y;
  const int q0 = blockIdx.x * 128 + w * 32;
  const int kvbase = blockIdx.z * 2048;
  const bf16* Qh = Q + (size_t)bh * 4096 * 64;
  const bf16* Kh = Kg + (size_t)bh * 4096 * 64;
  const bf16* Vh = VT + (size_t)bh * 64 * 4096;
  float* outp = blockIdx.z ? out1 : out0;

  const int sl = lane >> 3;
  const int ssc = ((lane & 7) ^ sl) * 8;           // pre-swizzled source col

  // global src pointers (advance by `step` per staged tile) + LDS dest offsets
  const bf16* gs[4];
  int dstoff[4], step;
  if (w < 2) {
#pragma unroll
    for (int c = 0; c < 4; ++c) {
      const int rho = (w * 4 + c) * 8 + sl;        // physical LDS row
      gs[c] = Kh + (size_t)(kvbase + sigma64(rho)) * 64 + ssc;  // sigma rows
      dstoff[c] = (w * 4 + c) * 512;
    }
    step = 64 * 64;                                // next kv chunk: +64 rows
  } else {
#pragma unroll
    for (int c = 0; c < 4; ++c) {
      const int d = ((w - 2) * 4 + c) * 8 + sl;    // VT row (d)
      gs[c] = Vh + (size_t)d * 4096 + kvbase + ssc;
      dstoff[c] = 8192 + ((w - 2) * 4 + c) * 512;
    }
    step = 64;                                     // next kv chunk: +64 cols
  }

  auto stageN = [&](int bi) {
#pragma unroll
    for (int c = 0; c < 4; ++c) {
      gload_lds16(gs[c], KV + bi * 4096 + dstoff[c]);
      gs[c] += step;
    }
  };

  // hoisted LDS read lane-offsets (elements): row=ql part + swizzled k-slot
  int lro[2];
#pragma unroll
  for (int kc = 0; kc < 2; ++kc)
    lro[kc] = ql * 64 + (((kc * 4 + hi) ^ (lane & 7)) * 8);

  bf16x8 qf[2][2];
#pragma unroll
  for (int qb = 0; qb < 2; ++qb)
#pragma unroll
    for (int kc = 0; kc < 2; ++kc)
      qf[qb][kc] = *reinterpret_cast<const bf16x8*>(
          &Qh[(size_t)(q0 + qb * 16 + ql) * 64 + kc * 32 + hi * 8]);

  f32x4 o[2][4];
#pragma unroll
  for (int qb = 0; qb < 2; ++qb)
#pragma unroll
    for (int db = 0; db < 4; ++db) o[qb][db] = {0.f, 0.f, 0.f, 0.f};

  stageN(0);                                       // tiles 0,1 in flight
  stageN(1);

  for (int it = 0; it < 32; ++it) {
    const int cur = it & 1;
    if (it < 31) {
      asm volatile("s_waitcnt vmcnt(4)" ::: "memory");   // tile t landed
    } else {
      asm volatile("s_waitcnt vmcnt(0)" ::: "memory");
    }
    __builtin_amdgcn_s_barrier();                  // all waves' tile-t ready

    const bf16* Kb = KV + cur * 4096;

    // S^T = K_staged Q^T : s[qb][kvb], lane: col=q=ql, rows=phys kv
    f32x4 s[2][4];
#pragma unroll
    for (int qb = 0; qb < 2; ++qb)
#pragma unroll
      for (int kvb = 0; kvb < 4; ++kvb) s[qb][kvb] = {0.f, 0.f, 0.f, 0.f};
#pragma unroll
    for (int kc = 0; kc < 2; ++kc) {
      const bf16* kbp = Kb + lro[kc];
      bf16x8 kf[4];
#pragma unroll
      for (int kvb = 0; kvb < 4; ++kvb)
        kf[kvb] = *reinterpret_cast<const bf16x8*>(kbp + kvb * 1024);
      __builtin_amdgcn_s_setprio(1);
#pragma unroll
      for (int qb = 0; qb < 2; ++qb)
#pragma unroll
        for (int kvb = 0; kvb < 4; ++kvb)
          s[qb][kvb] = mfma16(kf[kvb], qf[qb][kc], s[qb][kvb]);
      __builtin_amdgcn_s_setprio(0);
    }

    // PV: pack P in-register (sigma makes S^T frag == PV A-frag) and MFMA
#pragma unroll
    for (int kc = 0; kc < 2; ++kc) {
      const bf16* vbp = Kb + 8192 + lro[kc];
      bf16x8 vf[4];
#pragma unroll
      for (int db = 0; db < 4; ++db)
        vf[db] = *reinterpret_cast<const bf16x8*>(vbp + db * 1024);
      bf16x8 pa[2];
#pragma unroll
      for (int qb = 0; qb < 2; ++qb)
#pragma unroll
        for (int u = 0; u < 2; ++u)
#pragma unroll
          for (int r = 0; r < 4; ++r)
            pa[qb][u * 4 + r] = (bf16)fmaxf(s[qb][2 * kc + u][r], 0.f);
      __builtin_amdgcn_s_setprio(1);
#pragma unroll
      for (int qb = 0; qb < 2; ++qb)
#pragma unroll
        for (int db = 0; db < 4; ++db)
          o[qb][db] = mfma16(pa[qb], vf[db], o[qb][db]);
      __builtin_amdgcn_s_setprio(0);
    }

    __builtin_amdgcn_s_barrier();                  // all waves done with buf
    if (it + 2 < 32) stageN(cur);                  // tile t+2 into buf cur
  }

  const int b = bh >> 3, h = bh & 7;
#pragma unroll
  for (int qb = 0; qb < 2; ++qb)
#pragma unroll
    for (int db = 0; db < 4; ++db)
#pragma unroll
      for (int r = 0; r < 4; ++r) {
        const int n = q0 + qb * 16 + hi * 4 + r;
        const int dcol = db * 16 + ql;
        outp[((size_t)(b * 4096 + n)) * 512 + h * 64 + dcol] = o[qb][db][r] * 0.125f;
      }
}

// ---------- LayerNorm over 512 of (in0+in1), one wave per row, bf16 out ----
__global__ __launch_bounds__(256) void ln_kernel(const float* __restrict__ in0,
                                                 const float* __restrict__ in1,
                                                 const float* __restrict__ gamma,
                                                 const float* __restrict__ beta,
                                                 bf16* __restrict__ out) {
  const int lane = threadIdx.x & 63;
  const int w = threadIdx.x >> 6;
  const int row = blockIdx.x * 4 + w;
  const float* r0 = in0 + (size_t)row * 512;
  const float* r1 = in1 + (size_t)row * 512;
  f32x4 a = *reinterpret_cast<const f32x4*>(&r0[lane * 4]);
  f32x4 b = *reinterpret_cast<const f32x4*>(&r0[256 + lane * 4]);
  f32x4 a1 = *reinterpret_cast<const f32x4*>(&r1[lane * 4]);
  f32x4 b1 = *reinterpret_cast<const f32x4*>(&r1[256 + lane * 4]);
#pragma unroll
  for (int i = 0; i < 4; ++i) { a[i] += a1[i]; b[i] += b1[i]; }
  float s = a[0] + a[1] + a[2] + a[3] + b[0] + b[1] + b[2] + b[3];
  float ss = a[0] * a[0] + a[1] * a[1] + a[2] * a[2] + a[3] * a[3] +
             b[0] * b[0] + b[1] * b[1] + b[2] * b[2] + b[3] * b[3];
#pragma unroll
  for (int off = 32; off > 0; off >>= 1) {
    s += __shfl_xor(s, off);
    ss += __shfl_xor(ss, off);
  }
  const float mean = s * (1.f / 512.f);
  const float var = ss * (1.f / 512.f) - mean * mean;
  const float rstd = rsqrtf(var + 1e-5f);
  f32x4 g0 = *reinterpret_cast<const f32x4*>(&gamma[lane * 4]);
  f32x4 g1 = *reinterpret_cast<const f32x4*>(&gamma[256 + lane * 4]);
  f32x4 e0 = *reinterpret_cast<const f32x4*>(&beta[lane * 4]);
  f32x4 e1 = *reinterpret_cast<const f32x4*>(&beta[256 + lane * 4]);
  bf16x4 o0, o1;
#pragma unroll
  for (int i = 0; i < 4; ++i) {
    o0[i] = (bf16)((a[i] - mean) * rstd * g0[i] + e0[i]);
    o1[i] = (bf16)((b[i] - mean) * rstd * g1[i] + e1[i]);
  }
  *reinterpret_cast<bf16x4*>(&out[(size_t)row * 512 + lane * 4]) = o0;
  *reinterpret_cast<bf16x4*>(&out[(size_t)row * 512 + 256 + lane * 4]) = o1;
}

extern "C" void kernel_launch(void* const* d_in, const int* in_sizes, int n_in,
                              void* d_out, int out_size, void* d_ws, size_t ws_size,
                              hipStream_t stream) {
  const float* x = (const float*)d_in[0];       // [2,4096,512]
  const float* w_qkv = (const float*)d_in[1];   // [512,1536]
  const float* ln_g = (const float*)d_in[2];    // [512]
  const float* ln_b = (const float*)d_in[3];    // [512]
  const float* w_out = (const float*)d_in[4];   // [512,512]
  const float* b_out = (const float*)d_in[5];   // [512]
  float* out = (float*)d_out;                   // [2,4096,512] f32

  char* ws = (char*)d_ws;
  size_t off = 0;
  auto alloc = [&](size_t bytes) {
    void* p = ws + off;
    off += (bytes + 255) & ~(size_t)255;
    return p;
  };
  bf16* x_bf = (bf16*)alloc((size_t)8192 * 512 * 2);
  bf16* wqkvT = (bf16*)alloc((size_t)1536 * 512 * 2);
  bf16* woutT = (bf16*)alloc((size_t)512 * 512 * 2);
  bf16* qbuf = (bf16*)alloc((size_t)16 * 4096 * 64 * 2);
  bf16* kbuf = (bf16*)alloc((size_t)16 * 4096 * 64 * 2);
  bf16* vtbuf = (bf16*)alloc((size_t)16 * 64 * 4096 * 2);
  float* attn_out0 = (float*)alloc((size_t)8192 * 512 * 4);
  float* attn_out1 = (float*)alloc((size_t)8192 * 512 * 4);
  bf16* ln_bf = (bf16*)alloc((size_t)8192 * 512 * 2);

  // 1) prep: cvt + both weight transposes (one launch)
  prep_kernel<<<2304, 256, 0, stream>>>(x, x_bf, w_qkv, wqkvT, w_out, woutT);

  // 2) qkv = x @ w_qkv -> Q,K (row-major per head), V transposed [d][n]
  gemm_kernel<0><<<dim3(12, 64), 256, 0, stream>>>(x_bf, wqkvT, qbuf, kbuf, vtbuf,
                                                   nullptr, nullptr);

  // 3) fused relu-attention -> two partial f32 buffers (kv-split halves)
  attn_kernel<<<dim3(32, 16, 2), 256, 0, stream>>>(qbuf, kbuf, vtbuf,
                                                   attn_out0, attn_out1);

  // 4) layernorm(sum of halves) -> bf16
  ln_kernel<<<2048, 256, 0, stream>>>(attn_out0, attn_out1, ln_g, ln_b, ln_bf);

  // 5) out = ln @ w_out + b_out -> f32
  gemm_kernel<1><<<dim3(4, 64), 256, 0, stream>>>(ln_bf, woutT, nullptr, nullptr,
                                                  nullptr, b_out, out);
}